// Round 2
// baseline (365.291 us; speedup 1.0000x reference)
//
#include <hip/hip_runtime.h>

// WindowAttention: B_=4096 windows, N=49, DIM=128, NH=4, HD=32, nW=64.
// One block per window, 512 threads = 8 waves; wave w -> (head = w&3, m-half = w>>2).
// bf16 MFMA 16x16x32. S computed transposed (S^T = K*Q^T): softmax rows in-lane,
// P feeds PV as B-fragment via shuffles (no P LDS round-trip).
// R5 (= R4 with compile fix: integer RNE bf16 packing, no __hip_bfloat162 bit_cast):
//  - qk LDS layout d-slot-major [s][h][dslot][m][8] -> conflict-free qf/kf ds_read_b128
//  - comb precomputed as [w*4+h][m][64] f32 with -1e30 baked in pad cols -> float4
//    C-operand loads; bl=0's loads hoisted before the phase-1->2 barrier
//  - phase-1 weight fragments double-buffered (depth-1 prefetch)
//  - prep kernel fully parallel: one element per thread, coalesced mask reads

typedef short bf16x8 __attribute__((ext_vector_type(8)));
typedef float f32x4 __attribute__((ext_vector_type(4)));

#define DEVI __device__ __forceinline__

DEVI unsigned short f2b(float f) {   // fp32 -> bf16 bits, round-to-nearest-even
    unsigned u = __builtin_bit_cast(unsigned, f);
    u += 0x7fffu + ((u >> 16) & 1u);
    return (unsigned short)(u >> 16);
}

DEVI unsigned pack2(float lo, float hi) {  // two f32 -> packed bf16x2 (RNE)
    return (unsigned)f2b(lo) | ((unsigned)f2b(hi) << 16);
}

#define WS_BIAS_OFF 98304
#define WS_COMB_OFF 131072
#define COMB_ELEMS  802816u   // 256 * 49 * 64
#define WS_NEED     (131072u + COMB_ELEMS * 4u)

// prep: one element per thread.
//  g in [0, 49152)           : permuted bf16 weights, row c' = s*128+h*32+d
//  g in [49152, 49536)       : permuted (pre-scaled) bias
//  g in [49536, 49536+802816): comb[(w*4+h)][m][n64] = mask[w][m][n] + rel[m][n]
//                              (n in [49,64) baked to -1e30)
__global__ __launch_bounds__(256) void prep_kernel(
    const float* __restrict__ qkvw, const float* __restrict__ qkvb,
    const float* __restrict__ maskg, const float* __restrict__ relt,
    unsigned short* __restrict__ wb, float* __restrict__ bb,
    float* __restrict__ comb)
{
    const int g = blockIdx.x * 256 + threadIdx.x;
    if (g < 49152) {
        const int row = g >> 7, col = g & 127;
        const int s = row >> 7, r7 = row & 127, hh = r7 >> 5, d = r7 & 31;
        const int c = hh * 96 + d * 3 + s;          // torch row
        const float mul = (s == 0) ? 0.17677669529663687f : 1.0f;
        wb[row * 128 + col] = f2b(qkvw[c * 128 + col] * mul);
    } else if (g < 49536) {
        const int row = g - 49152;
        const int s = row >> 7, r7 = row & 127, hh = r7 >> 5, d = r7 & 31;
        const int c = hh * 96 + d * 3 + s;
        const float mul = (s == 0) ? 0.17677669529663687f : 1.0f;
        bb[row] = qkvb[c] * mul;
    } else {
        const unsigned g2 = (unsigned)(g - 49536);
        if (g2 < COMB_ELEMS) {
            const int wh = g2 / 3136;
            const int rr = g2 - wh * 3136;
            const int m = rr >> 6, n = rr & 63;
            const int w = wh >> 2, hh = wh & 3;
            float v = -1e30f;
            if (n < 49) {
                const int md = m / 7, mm = m - md * 7;
                const int nd = n / 7, nm = n - nd * 7;
                const int ridx = (md - nd + 6) * 13 + (mm - nm + 6);
                v = maskg[w * 2401 + m * 49 + n] + relt[ridx * 4 + hh];
            }
            comb[g2] = v;
        }
    }
}

// LDS: 32768 + 18432 = 51200 B -> 3 blocks/CU (24 waves/CU).
struct __align__(16) Smem {
    unsigned short qk[2][4][4][64][8];  // [q/k][head][dslot=d>>3][m][d&7]; Q pre-scaled
    union {
        unsigned short xs[64][136];     // staged x, 272 B rows
        unsigned short vt[4][32][72];   // V^T [head][d][n], 144 B rows
    } b;
};

template <bool USE_WS>
__global__ __launch_bounds__(512, 6) void wattn_kernel(
    const float* __restrict__ xg, const unsigned short* __restrict__ wb,
    const float* __restrict__ bb, const float* __restrict__ comb,
    const float* __restrict__ maskg, const float* __restrict__ qkvw,
    const float* __restrict__ qkvb, const float* __restrict__ relt,
    float* __restrict__ outg)
{
    __shared__ Smem sm;
    const int tid  = threadIdx.x;
    const int lane = tid & 63;
    const int wv   = tid >> 6;       // 0..7
    const int h    = wv & 3;         // head
    const int half = wv >> 2;        // m-half
    const int lr   = lane & 15;
    const int lq   = lane >> 4;
    const int bI   = blockIdx.x;

    // ---------------- phase 0: stage x (bf16) into LDS ----------------
    const float* xb = xg + (size_t)bI * 6272;
    #pragma unroll
    for (int it = 0; it < 4; ++it) {
        int i = it * 512 + tid;
        if (i < 1568) {
            float4 v = ((const float4*)xb)[i];
            int row = i >> 5, col = (i & 31) << 2;
            *(uint2*)&sm.b.xs[row][col] = make_uint2(pack2(v.x, v.y), pack2(v.z, v.w));
        }
    }
    if (tid < 480) {                 // zero rows 49..63
        int idx = tid << 2;
        *(ushort4*)&sm.b.xs[49 + (idx >> 7)][idx & 127] = make_ushort4(0, 0, 0, 0);
    }
    __syncthreads();

    // ---------------- phase 1: QKV projection ----------------
    bf16x8 af[4][2];
    #pragma unroll
    for (int ks = 0; ks < 4; ++ks)
        #pragma unroll
        for (int mtl = 0; mtl < 2; ++mtl)
            af[ks][mtl] = *(const bf16x8*)&sm.b.xs[(half * 2 + mtl) * 16 + lr][ks * 32 + lq * 8];
    __syncthreads();                 // xs dead -> vt region may be written

    if constexpr (USE_WS) {
        // permuted weights: tile j -> (s = j>>1, dhalf = j&1), channel lane-linear.
        // depth-1 double buffer: loads for j+1 issued before j's MFMAs.
        bf16x8 wcur[4];
        {
            const int cp0 = h * 32 + lr;   // j=0: s=0, dh=0
            #pragma unroll
            for (int ks = 0; ks < 4; ++ks)
                wcur[ks] = *(const bf16x8*)&wb[cp0 * 128 + ks * 32 + lq * 8];
        }
        #pragma unroll
        for (int j = 0; j < 6; ++j) {
            const int s = j >> 1, dh = j & 1;
            const int dd = dh * 16 + lr;
            const int cp = s * 128 + h * 32 + dd;
            const float bc = bb[cp];
            bf16x8 wnxt[4];
            if (j < 5) {
                const int jn = j + 1;
                const int cpn = (jn >> 1) * 128 + h * 32 + (jn & 1) * 16 + lr;
                #pragma unroll
                for (int ks = 0; ks < 4; ++ks)
                    wnxt[ks] = *(const bf16x8*)&wb[cpn * 128 + ks * 32 + lq * 8];
            }
            f32x4 acc[2];
            acc[0] = f32x4{0.f, 0.f, 0.f, 0.f};
            acc[1] = f32x4{0.f, 0.f, 0.f, 0.f};
            #pragma unroll
            for (int ks = 0; ks < 4; ++ks)
                #pragma unroll
                for (int mtl = 0; mtl < 2; ++mtl)
                    acc[mtl] = __builtin_amdgcn_mfma_f32_16x16x32_bf16(af[ks][mtl], wcur[ks], acc[mtl], 0, 0, 0);
            #pragma unroll
            for (int mtl = 0; mtl < 2; ++mtl) {
                const int m0 = (half * 2 + mtl) * 16 + lq * 4;
                const unsigned p01 = pack2(acc[mtl][0] + bc, acc[mtl][1] + bc);
                const unsigned p23 = pack2(acc[mtl][2] + bc, acc[mtl][3] + bc);
                if (s == 2) {
                    *(uint2*)&sm.b.vt[h][dd][m0] = make_uint2(p01, p23);
                } else {
                    unsigned short* qp = &sm.qk[s][h][dh * 2 + (lr >> 3)][m0][lr & 7];
                    qp[0]  = (unsigned short)p01;
                    qp[8]  = (unsigned short)(p01 >> 16);
                    qp[16] = (unsigned short)p23;
                    qp[24] = (unsigned short)(p23 >> 16);
                }
            }
            if (j < 5) {
                #pragma unroll
                for (int ks = 0; ks < 4; ++ks) wcur[ks] = wnxt[ks];
            }
        }
    } else {
        // fallback: same tile mapping, weights loaded (and scaled) from qkvw
        #pragma unroll
        for (int j = 0; j < 6; ++j) {
            const int s = j >> 1, dh = j & 1;
            const int dd = dh * 16 + lr;
            const int c = h * 96 + dd * 3 + s;        // torch row for channel cp
            const float mul = (s == 0) ? 0.17677669529663687f : 1.0f;
            const float bc = qkvb[c] * mul;
            f32x4 acc[2];
            acc[0] = f32x4{0.f, 0.f, 0.f, 0.f};
            acc[1] = f32x4{0.f, 0.f, 0.f, 0.f};
            #pragma unroll
            for (int ks = 0; ks < 4; ++ks) {
                const float4* wp = (const float4*)(qkvw + c * 128 + ks * 32 + lq * 8);
                float4 w0 = wp[0], w1 = wp[1];
                union { unsigned u[4]; bf16x8 v; } tw;
                tw.u[0] = pack2(w0.x * mul, w0.y * mul);
                tw.u[1] = pack2(w0.z * mul, w0.w * mul);
                tw.u[2] = pack2(w1.x * mul, w1.y * mul);
                tw.u[3] = pack2(w1.z * mul, w1.w * mul);
                #pragma unroll
                for (int mtl = 0; mtl < 2; ++mtl)
                    acc[mtl] = __builtin_amdgcn_mfma_f32_16x16x32_bf16(af[ks][mtl], tw.v, acc[mtl], 0, 0, 0);
            }
            #pragma unroll
            for (int mtl = 0; mtl < 2; ++mtl) {
                const int m0 = (half * 2 + mtl) * 16 + lq * 4;
                const unsigned p01 = pack2(acc[mtl][0] + bc, acc[mtl][1] + bc);
                const unsigned p23 = pack2(acc[mtl][2] + bc, acc[mtl][3] + bc);
                if (s == 2) {
                    *(uint2*)&sm.b.vt[h][dd][m0] = make_uint2(p01, p23);
                } else {
                    unsigned short* qp = &sm.qk[s][h][dh * 2 + (lr >> 3)][m0][lr & 7];
                    qp[0]  = (unsigned short)p01;
                    qp[8]  = (unsigned short)(p01 >> 16);
                    qp[16] = (unsigned short)p23;
                    qp[24] = (unsigned short)(p23 >> 16);
                }
            }
        }
    }

    // hoist bl=0's bias C-operand loads before the barrier (completed by the
    // barrier's vmcnt drain -> off the post-barrier critical path)
    const float* cwh = comb + (size_t)((bI & 63) * 4 + h) * 3136;
    const float* mw  = maskg + (size_t)(bI & 63) * 2401;
    f32x4 cc0[4];
    if constexpr (USE_WS) {
        const int m0b = (half * 2) * 16 + lr;
        const int mi0 = m0b < 48 ? m0b : 48;
        const float* cr = cwh + mi0 * 64;
        #pragma unroll
        for (int a = 0; a < 4; ++a)
            cc0[a] = *(const f32x4*)&cr[a * 16 + lq * 4];
    }
    __syncthreads();

    // ---------------- phase 2: attention ----------------
    bf16x8 kf[4];
    #pragma unroll
    for (int t = 0; t < 4; ++t)
        kf[t] = *(const bf16x8*)&sm.qk[1][h][lq][t * 16 + lr][0];

    float* ob = outg + (size_t)bI * 6272;
    const int src0 = ((lq & 1) * 2) * 16 + lr;
    const int src1 = src0 + 16;
    const bool up  = (lq >= 2);

    #pragma unroll
    for (int bl = 0; bl < 2; ++bl) {
        const int mt = half * 2 + bl;
        const int m  = mt * 16 + lr;
        const int mi = m < 48 ? m : 48;

        f32x4 st[4];
        bf16x8 qf = *(const bf16x8*)&sm.qk[0][h][lq][m][0];
        if constexpr (USE_WS) {
            f32x4 cc[4];
            if (bl == 0) {
                #pragma unroll
                for (int a = 0; a < 4; ++a) cc[a] = cc0[a];
            } else {
                const float* cr = cwh + mi * 64;
                #pragma unroll
                for (int a = 0; a < 4; ++a)
                    cc[a] = *(const f32x4*)&cr[a * 16 + lq * 4];
            }
            #pragma unroll
            for (int a = 0; a < 4; ++a)
                st[a] = __builtin_amdgcn_mfma_f32_16x16x32_bf16(kf[a], qf, cc[a], 0, 0, 0);
        } else {
            #pragma unroll
            for (int a = 0; a < 4; ++a) {
                f32x4 z = f32x4{0.f, 0.f, 0.f, 0.f};
                st[a] = __builtin_amdgcn_mfma_f32_16x16x32_bf16(kf[a], qf, z, 0, 0, 0);
            }
            const int md = mi / 7, mm = mi - md * 7;
            #pragma unroll
            for (int a = 0; a < 4; ++a)
                #pragma unroll
                for (int r = 0; r < 4; ++r) {
                    int n = a * 16 + lq * 4 + r;
                    int ni = n < 48 ? n : 48;
                    int nd = ni / 7, nm = ni - nd * 7;
                    int ridx = (md - nd + 6) * 13 + (mm - nm + 6);
                    float v = st[a][r] + relt[ridx * 4 + h] + mw[mi * 49 + ni];
                    st[a][r] = (n < 49) ? v : -1e30f;
                }
        }

        // softmax over row m (16 in-lane + lanes {lr, lr+16, lr+32, lr+48})
        float mx = -3.4e38f;
        #pragma unroll
        for (int a = 0; a < 4; ++a)
            #pragma unroll
            for (int r = 0; r < 4; ++r) mx = fmaxf(mx, st[a][r]);
        mx = fmaxf(mx, __shfl_xor(mx, 16));
        mx = fmaxf(mx, __shfl_xor(mx, 32));
        float sum = 0.f;
        #pragma unroll
        for (int a = 0; a < 4; ++a)
            #pragma unroll
            for (int r = 0; r < 4; ++r) {
                float e = __expf(st[a][r] - mx);
                st[a][r] = e;
                sum += e;
            }
        sum += __shfl_xor(sum, 16);
        sum += __shfl_xor(sum, 32);
        const float inv = 1.f / sum;

        unsigned pk[4][2];
        #pragma unroll
        for (int a = 0; a < 4; ++a) {
            pk[a][0] = pack2(st[a][0] * inv, st[a][1] * inv);
            pk[a][1] = pack2(st[a][2] * inv, st[a][3] * inv);
        }

        // PV: out^T[d][m] = sum_n Vt[d][n] * P[m][n]; P B-frag via shuffles
        f32x4 o[2];
        o[0] = f32x4{0.f, 0.f, 0.f, 0.f};
        o[1] = f32x4{0.f, 0.f, 0.f, 0.f};
        #pragma unroll
        for (int kt = 0; kt < 2; ++kt) {
            unsigned ea0 = (unsigned)__shfl((int)pk[2 * kt][0], src0);
            unsigned ea1 = (unsigned)__shfl((int)pk[2 * kt][1], src0);
            unsigned ea2 = (unsigned)__shfl((int)pk[2 * kt][0], src1);
            unsigned ea3 = (unsigned)__shfl((int)pk[2 * kt][1], src1);
            unsigned eb0 = (unsigned)__shfl((int)pk[2 * kt + 1][0], src0);
            unsigned eb1 = (unsigned)__shfl((int)pk[2 * kt + 1][1], src0);
            unsigned eb2 = (unsigned)__shfl((int)pk[2 * kt + 1][0], src1);
            unsigned eb3 = (unsigned)__shfl((int)pk[2 * kt + 1][1], src1);
            union { unsigned u[4]; bf16x8 v; } pu;
            pu.u[0] = up ? eb0 : ea0;
            pu.u[1] = up ? eb1 : ea1;
            pu.u[2] = up ? eb2 : ea2;
            pu.u[3] = up ? eb3 : ea3;
            #pragma unroll
            for (int dt = 0; dt < 2; ++dt) {
                bf16x8 vf = *(const bf16x8*)&sm.b.vt[h][dt * 16 + lr][kt * 32 + lq * 8];
                o[dt] = __builtin_amdgcn_mfma_f32_16x16x32_bf16(vf, pu.v, o[dt], 0, 0, 0);
            }
        }

        if (m < 49) {
            #pragma unroll
            for (int dt = 0; dt < 2; ++dt) {
                float4 v = make_float4(o[dt][0], o[dt][1], o[dt][2], o[dt][3]);
                *(float4*)&ob[m * 128 + h * 32 + dt * 16 + lq * 4] = v;
            }
        }
    }
}

extern "C" void kernel_launch(void* const* d_in, const int* in_sizes, int n_in,
                              void* d_out, int out_size, void* d_ws, size_t ws_size,
                              hipStream_t stream) {
    const float* x    = (const float*)d_in[0];
    const float* mask = (const float*)d_in[1];
    const float* qkvw = (const float*)d_in[2];
    const float* qkvb = (const float*)d_in[3];
    const float* relt = (const float*)d_in[4];
    float* out = (float*)d_out;

    if (d_ws != nullptr && ws_size >= (size_t)WS_NEED) {
        unsigned short* wbf = (unsigned short*)d_ws;
        float* bbf  = (float*)((char*)d_ws + WS_BIAS_OFF);
        float* comb = (float*)((char*)d_ws + WS_COMB_OFF);
        // elements: 49152 weights + 384 bias + 802816 comb = 852352 -> 3330 blocks
        prep_kernel<<<3330, 256, 0, stream>>>(qkvw, qkvb, mask, relt, wbf, bbf, comb);
        wattn_kernel<true><<<4096, 512, 0, stream>>>(x, wbf, bbf, comb, mask, qkvw, qkvb, relt, out);
    } else {
        wattn_kernel<false><<<4096, 512, 0, stream>>>(x, nullptr, nullptr, nullptr, mask, qkvw, qkvb, relt, out);
    }
}

// Round 5
// 274.605 us; speedup vs baseline: 1.3302x; 1.3302x over previous
//
#include <hip/hip_runtime.h>

// WindowAttention: B_=4096 windows, N=49, DIM=128, NH=4, HD=32, nW=64.
// One block per window, 512 threads = 8 waves; wave w -> (head = w&3, m-half = w>>2).
// bf16 MFMA 16x16x32. S computed transposed (S^T = K*Q^T): softmax rows in-lane,
// P feeds PV as B-fragment via shuffles (no P LDS round-trip).
// R6 = R3 (verified 140us wattn) + two register-neutral deltas:
//  - comb precomputed as [w*4+h][m][64] f32 with -1e30 baked into pad cols ->
//    phase-2 C-operand is 4x float4 loads (was 16 scattered dword gathers/lane).
//    No hoist across barriers, no prefetch: zero added live registers.
//  - prep kernel fully parallel (one element per thread).
// R5 post-mortem: weight double-buffer + cc0 barrier-hoist exceeded the ~85-reg
// unified VGPR+AGPR cap (launch_bounds 512,6) -> 340 MB scratch spill writes.

typedef short bf16x8 __attribute__((ext_vector_type(8)));
typedef float f32x4 __attribute__((ext_vector_type(4)));

#define DEVI __device__ __forceinline__

DEVI unsigned short f2b(float f) {   // fp32 -> bf16 bits, round-to-nearest-even
    unsigned u = __builtin_bit_cast(unsigned, f);
    u += 0x7fffu + ((u >> 16) & 1u);
    return (unsigned short)(u >> 16);
}

#define WS_BIAS_OFF 98304
#define WS_COMB_OFF 131072
#define COMB_ELEMS  802816u   // 256 * 49 * 64 (padded n-dim to 64)
#define WS_NEED     (131072u + COMB_ELEMS * 4u)

// prep: one element per thread.
//  g in [0, 49152)           : permuted bf16 weights, row c' = s*128+h*32+d
//  g in [49152, 49536)       : permuted (pre-scaled) bias
//  g in [49536, 49536+802816): comb[(w*4+h)][m][n64] = mask[w][m][n] + rel[m][n]
//                              (n in [49,64) baked to -1e30)
__global__ __launch_bounds__(256) void prep_kernel(
    const float* __restrict__ qkvw, const float* __restrict__ qkvb,
    const float* __restrict__ maskg, const float* __restrict__ relt,
    unsigned short* __restrict__ wb, float* __restrict__ bb,
    float* __restrict__ comb)
{
    const int g = blockIdx.x * 256 + threadIdx.x;
    if (g < 49152) {
        const int row = g >> 7, col = g & 127;
        const int s = row >> 7, r7 = row & 127, hh = r7 >> 5, d = r7 & 31;
        const int c = hh * 96 + d * 3 + s;          // torch row
        const float mul = (s == 0) ? 0.17677669529663687f : 1.0f;
        wb[row * 128 + col] = f2b(qkvw[c * 128 + col] * mul);
    } else if (g < 49536) {
        const int row = g - 49152;
        const int s = row >> 7, r7 = row & 127, hh = r7 >> 5, d = r7 & 31;
        const int c = hh * 96 + d * 3 + s;
        const float mul = (s == 0) ? 0.17677669529663687f : 1.0f;
        bb[row] = qkvb[c] * mul;
    } else {
        const unsigned g2 = (unsigned)(g - 49536);
        if (g2 < COMB_ELEMS) {
            const int wh = g2 / 3136;
            const int rr = g2 - wh * 3136;
            const int m = rr >> 6, n = rr & 63;
            const int w = wh >> 2, hh = wh & 3;
            float v = -1e30f;
            if (n < 49) {
                const int md = m / 7, mm = m - md * 7;
                const int nd = n / 7, nm = n - nd * 7;
                const int ridx = (md - nd + 6) * 13 + (mm - nm + 6);
                v = maskg[w * 2401 + m * 49 + n] + relt[ridx * 4 + hh];
            }
            comb[g2] = v;
        }
    }
}

// LDS: 32768 + 18432 = 51200 B -> 3 blocks/CU (24 waves/CU).
struct __align__(16) Smem {
    unsigned short qk[2][4][64][32];   // [q/k][head][m][d]; Q pre-scaled
    union {
        unsigned short xs[64][136];    // staged x, 272 B rows
        unsigned short vt[4][32][72];  // V^T [head][d][n], 144 B rows
    } b;
};

template <bool USE_WS>
__global__ __launch_bounds__(512, 6) void wattn_kernel(
    const float* __restrict__ xg, const unsigned short* __restrict__ wb,
    const float* __restrict__ bb, const float* __restrict__ comb,
    const float* __restrict__ maskg, const float* __restrict__ qkvw,
    const float* __restrict__ qkvb, const float* __restrict__ relt,
    float* __restrict__ outg)
{
    __shared__ Smem sm;
    const int tid  = threadIdx.x;
    const int lane = tid & 63;
    const int wv   = tid >> 6;       // 0..7
    const int h    = wv & 3;         // head
    const int half = wv >> 2;        // m-half
    const int lr   = lane & 15;
    const int lq   = lane >> 4;
    const int bI   = blockIdx.x;

    // ---------------- phase 0: stage x (bf16) into LDS ----------------
    const float* xb = xg + (size_t)bI * 6272;
    #pragma unroll
    for (int it = 0; it < 4; ++it) {
        int i = it * 512 + tid;
        if (i < 1568) {
            float4 v = ((const float4*)xb)[i];
            int row = i >> 5, col = (i & 31) << 2;
            *(ushort4*)&sm.b.xs[row][col] =
                make_ushort4(f2b(v.x), f2b(v.y), f2b(v.z), f2b(v.w));
        }
    }
    if (tid < 480) {                 // zero rows 49..63
        int idx = tid << 2;
        *(ushort4*)&sm.b.xs[49 + (idx >> 7)][idx & 127] = make_ushort4(0, 0, 0, 0);
    }
    __syncthreads();

    // ---------------- phase 1: QKV projection ----------------
    bf16x8 af[4][2];
    #pragma unroll
    for (int ks = 0; ks < 4; ++ks)
        #pragma unroll
        for (int mtl = 0; mtl < 2; ++mtl)
            af[ks][mtl] = *(const bf16x8*)&sm.b.xs[(half * 2 + mtl) * 16 + lr][ks * 32 + lq * 8];
    __syncthreads();                 // xs dead -> vt region may be written

    if constexpr (USE_WS) {
        // permuted weights: tile j -> (s = j>>1, dhalf = j&1), channel lane-linear
        #pragma unroll
        for (int j = 0; j < 6; ++j) {
            const int s     = j >> 1;
            const int dhalf = j & 1;
            const int cp    = s * 128 + h * 32 + dhalf * 16 + lr;
            const int dd    = dhalf * 16 + lr;
            const float bc  = bb[cp];
            f32x4 acc[2];
            acc[0] = f32x4{0.f, 0.f, 0.f, 0.f};
            acc[1] = f32x4{0.f, 0.f, 0.f, 0.f};
            #pragma unroll
            for (int ks = 0; ks < 4; ++ks) {
                bf16x8 bf = *(const bf16x8*)&wb[cp * 128 + ks * 32 + lq * 8];
                #pragma unroll
                for (int mtl = 0; mtl < 2; ++mtl)
                    acc[mtl] = __builtin_amdgcn_mfma_f32_16x16x32_bf16(af[ks][mtl], bf, acc[mtl], 0, 0, 0);
            }
            #pragma unroll
            for (int mtl = 0; mtl < 2; ++mtl) {
                const int m0 = (half * 2 + mtl) * 16 + lq * 4;
                if (s == 2) {
                    *(ushort4*)&sm.b.vt[h][dd][m0] =
                        make_ushort4(f2b(acc[mtl][0] + bc), f2b(acc[mtl][1] + bc),
                                     f2b(acc[mtl][2] + bc), f2b(acc[mtl][3] + bc));
                } else {
                    #pragma unroll
                    for (int r = 0; r < 4; ++r)
                        sm.qk[s][h][m0 + r][dd] = f2b(acc[mtl][r] + bc);
                }
            }
        }
    } else {
        // fallback: unpermuted weights, scalar scatter (R2 path)
        unsigned short* sbase = (unsigned short*)&sm;
        #pragma unroll
        for (int j = 0; j < 6; ++j) {
            const int c = (h * 6 + j) * 16 + lr;
            const float bc = qkvb[c];
            const int rem = j * 16 + lr;
            const int dd = rem / 3, s = rem % 3;
            const float mulv = (s == 0) ? 0.17677669529663687f : 1.0f;
            f32x4 acc[2];
            acc[0] = f32x4{0.f, 0.f, 0.f, 0.f};
            acc[1] = f32x4{0.f, 0.f, 0.f, 0.f};
            #pragma unroll
            for (int ks = 0; ks < 4; ++ks) {
                const float4* wp = (const float4*)(qkvw + c * 128 + ks * 32 + lq * 8);
                float4 w0 = wp[0], w1 = wp[1];
                bf16x8 t;
                t[0] = (short)f2b(w0.x); t[1] = (short)f2b(w0.y);
                t[2] = (short)f2b(w0.z); t[3] = (short)f2b(w0.w);
                t[4] = (short)f2b(w1.x); t[5] = (short)f2b(w1.y);
                t[6] = (short)f2b(w1.z); t[7] = (short)f2b(w1.w);
                #pragma unroll
                for (int mtl = 0; mtl < 2; ++mtl)
                    acc[mtl] = __builtin_amdgcn_mfma_f32_16x16x32_bf16(af[ks][mtl], t, acc[mtl], 0, 0, 0);
            }
            #pragma unroll
            for (int mtl = 0; mtl < 2; ++mtl)
                #pragma unroll
                for (int r = 0; r < 4; ++r) {
                    int m = (half * 2 + mtl) * 16 + lq * 4 + r;
                    int soff = (s == 2) ? (16384 + (h * 32 + dd) * 72 + m)
                                        : (s * 8192 + h * 2048 + m * 32 + dd);
                    sbase[soff] = f2b((acc[mtl][r] + bc) * mulv);
                }
        }
    }
    __syncthreads();

    // ---------------- phase 2: attention ----------------
    bf16x8 kf[4];
    #pragma unroll
    for (int t = 0; t < 4; ++t)
        kf[t] = *(const bf16x8*)&sm.qk[1][h][t * 16 + lr][lq * 8];

    const float* cwh = comb + (size_t)((bI & 63) * 4 + h) * 3136;
    const float* mw  = maskg + (size_t)(bI & 63) * 2401;
    float* ob = outg + (size_t)bI * 6272;
    const int src0 = ((lq & 1) * 2) * 16 + lr;
    const int src1 = src0 + 16;
    const bool up  = (lq >= 2);

    #pragma unroll
    for (int bl = 0; bl < 2; ++bl) {
        const int mt = half * 2 + bl;
        const int m  = mt * 16 + lr;
        const int mi = m < 48 ? m : 48;

        f32x4 st[4];
        bf16x8 qf = *(const bf16x8*)&sm.qk[0][h][m][lq * 8];
        if constexpr (USE_WS) {
            // C-operand: comb[m][n] row, contiguous float4 over n (pads = -1e30)
            const float* cr = cwh + mi * 64;
            f32x4 cc[4];
            #pragma unroll
            for (int a = 0; a < 4; ++a)
                cc[a] = *(const f32x4*)&cr[a * 16 + lq * 4];
            #pragma unroll
            for (int a = 0; a < 4; ++a)
                st[a] = __builtin_amdgcn_mfma_f32_16x16x32_bf16(kf[a], qf, cc[a], 0, 0, 0);
        } else {
            #pragma unroll
            for (int a = 0; a < 4; ++a) {
                f32x4 z = f32x4{0.f, 0.f, 0.f, 0.f};
                st[a] = __builtin_amdgcn_mfma_f32_16x16x32_bf16(kf[a], qf, z, 0, 0, 0);
            }
            const int md = mi / 7, mm = mi - md * 7;
            #pragma unroll
            for (int a = 0; a < 4; ++a)
                #pragma unroll
                for (int r = 0; r < 4; ++r) {
                    int n = a * 16 + lq * 4 + r;
                    int ni = n < 48 ? n : 48;
                    int nd = ni / 7, nm = ni - nd * 7;
                    int ridx = (md - nd + 6) * 13 + (mm - nm + 6);
                    float v = st[a][r] + relt[ridx * 4 + h] + mw[mi * 49 + ni];
                    st[a][r] = (n < 49) ? v : -1e30f;
                }
        }

        // softmax over row m (16 in-lane + lanes {lr, lr+16, lr+32, lr+48})
        float mx = -3.4e38f;
        #pragma unroll
        for (int a = 0; a < 4; ++a)
            #pragma unroll
            for (int r = 0; r < 4; ++r) mx = fmaxf(mx, st[a][r]);
        mx = fmaxf(mx, __shfl_xor(mx, 16));
        mx = fmaxf(mx, __shfl_xor(mx, 32));
        float sum = 0.f;
        #pragma unroll
        for (int a = 0; a < 4; ++a)
            #pragma unroll
            for (int r = 0; r < 4; ++r) {
                float e = __expf(st[a][r] - mx);
                st[a][r] = e;
                sum += e;
            }
        sum += __shfl_xor(sum, 16);
        sum += __shfl_xor(sum, 32);
        const float inv = 1.f / sum;

        unsigned pk[4][2];
        #pragma unroll
        for (int a = 0; a < 4; ++a) {
            pk[a][0] = (unsigned)f2b(st[a][0] * inv) | ((unsigned)f2b(st[a][1] * inv) << 16);
            pk[a][1] = (unsigned)f2b(st[a][2] * inv) | ((unsigned)f2b(st[a][3] * inv) << 16);
        }

        // PV: out^T[d][m] = sum_n Vt[d][n] * P[m][n]; P B-frag via shuffles
        f32x4 o[2];
        o[0] = f32x4{0.f, 0.f, 0.f, 0.f};
        o[1] = f32x4{0.f, 0.f, 0.f, 0.f};
        #pragma unroll
        for (int kt = 0; kt < 2; ++kt) {
            unsigned ea0 = (unsigned)__shfl((int)pk[2 * kt][0], src0);
            unsigned ea1 = (unsigned)__shfl((int)pk[2 * kt][1], src0);
            unsigned ea2 = (unsigned)__shfl((int)pk[2 * kt][0], src1);
            unsigned ea3 = (unsigned)__shfl((int)pk[2 * kt][1], src1);
            unsigned eb0 = (unsigned)__shfl((int)pk[2 * kt + 1][0], src0);
            unsigned eb1 = (unsigned)__shfl((int)pk[2 * kt + 1][1], src0);
            unsigned eb2 = (unsigned)__shfl((int)pk[2 * kt + 1][0], src1);
            unsigned eb3 = (unsigned)__shfl((int)pk[2 * kt + 1][1], src1);
            union { unsigned u[4]; bf16x8 v; } pu;
            pu.u[0] = up ? eb0 : ea0;
            pu.u[1] = up ? eb1 : ea1;
            pu.u[2] = up ? eb2 : ea2;
            pu.u[3] = up ? eb3 : ea3;
            #pragma unroll
            for (int dt = 0; dt < 2; ++dt) {
                bf16x8 vf = *(const bf16x8*)&sm.b.vt[h][dt * 16 + lr][kt * 32 + lq * 8];
                o[dt] = __builtin_amdgcn_mfma_f32_16x16x32_bf16(vf, pu.v, o[dt], 0, 0, 0);
            }
        }

        if (m < 49) {
            #pragma unroll
            for (int dt = 0; dt < 2; ++dt) {
                float4 v = make_float4(o[dt][0], o[dt][1], o[dt][2], o[dt][3]);
                *(float4*)&ob[m * 128 + h * 32 + dt * 16 + lq * 4] = v;
            }
        }
    }
}

extern "C" void kernel_launch(void* const* d_in, const int* in_sizes, int n_in,
                              void* d_out, int out_size, void* d_ws, size_t ws_size,
                              hipStream_t stream) {
    const float* x    = (const float*)d_in[0];
    const float* mask = (const float*)d_in[1];
    const float* qkvw = (const float*)d_in[2];
    const float* qkvb = (const float*)d_in[3];
    const float* relt = (const float*)d_in[4];
    float* out = (float*)d_out;

    if (d_ws != nullptr && ws_size >= (size_t)WS_NEED) {
        unsigned short* wbf = (unsigned short*)d_ws;
        float* bbf  = (float*)((char*)d_ws + WS_BIAS_OFF);
        float* comb = (float*)((char*)d_ws + WS_COMB_OFF);
        // elements: 49152 weights + 384 bias + 802816 comb = 852352 -> 3330 blocks
        prep_kernel<<<3330, 256, 0, stream>>>(qkvw, qkvb, mask, relt, wbf, bbf, comb);
        wattn_kernel<true><<<4096, 512, 0, stream>>>(x, wbf, bbf, comb, mask, qkvw, qkvb, relt, out);
    } else {
        wattn_kernel<false><<<4096, 512, 0, stream>>>(x, nullptr, nullptr, nullptr, mask, qkvw, qkvb, relt, out);
    }
}